// Round 18
// baseline (1463.215 us; speedup 1.0000x reference)
//
#include <hip/hip_runtime.h>
#include <hip/hip_fp16.h>

// B=64, T=128, U=256, D_in=32, SKIP=4; dense: (64 x 32768) @ (32768 x 4096)

__device__ __forceinline__ float sigmoidf_(float x) {
    return 1.0f / (1.0f + __expf(-x));
}
__device__ __forceinline__ float tanhf_(float x) {
    float xc = fminf(fmaxf(x, -15.f), 15.f);
    float e = __expf(2.f * xc);
    return (e - 1.f) / (e + 1.f);
}
__device__ __forceinline__ unsigned pkh(float lo, float hi) {
    __half2 h = __halves2half2(__float2half(lo), __float2half(hi));
    return *reinterpret_cast<unsigned*>(&h);
}
__device__ __forceinline__ float2 uph(unsigned u) {
    __half2 h = *reinterpret_cast<__half2*>(&u);
    return __half22float2(h);
}

// ---------------- all weight packing + flag zeroing ----------------
__global__ __launch_bounds__(256) void packall(
    const float* __restrict__ e_rk, const float* __restrict__ d_rk,
    const float* __restrict__ d_k,  const float* __restrict__ e_k,
    const float* __restrict__ e_k2, const float* __restrict__ d_k2,
    float4* __restrict__ rk4e, float4* __restrict__ rk4d,
    float4* __restrict__ dk4,  float4* __restrict__ ek4,
    unsigned* __restrict__ kh2e, unsigned* __restrict__ kh2d,
    unsigned* __restrict__ flags)
{
    const int bx = blockIdx.x, v = threadIdx.x;
    if (bx < 800) {
        const float* src; float4* dst; int row;
        if (bx < 256)      { src = e_rk; dst = rk4e; row = bx; }
        else if (bx < 512) { src = d_rk; dst = rk4d; row = bx - 256; }
        else if (bx < 768) { src = d_k;  dst = dk4;  row = bx - 512; }
        else               { src = e_k;  dst = ek4;  row = bx - 768; }
        const float* s = src + (size_t)row * 1024;
        dst[row * 256 + v] = make_float4(s[v], s[256 + v], s[512 + v], s[768 + v]);
    } else if (bx < 928) {
        const int u2 = bx - 800;   // 0..127
        kh2e[u2 * 256 + v] = pkh(e_k2[(2 * u2) * 256 + v], e_k2[(2 * u2 + 1) * 256 + v]);
        kh2d[u2 * 256 + v] = pkh(d_k2[(2 * u2) * 256 + v], d_k2[(2 * u2 + 1) * 256 + v]);
    } else {
        flags[v] = 0u;             // 256 flags, re-zeroed every launch (graph-safe)
    }
}

// ---------------- enc xW GEMM: K=32 rows gathered from X[:,0] ----------------
__global__ __launch_bounds__(256) void xw_gemm_enc(
    const float*  __restrict__ X,
    const float4* __restrict__ ek4,
    const float*  __restrict__ bias,
    float4* __restrict__ xWp)
{
    const int v = threadIdx.x;
    const int r0 = blockIdx.x * 16;
    __shared__ float se[16][32];

    #pragma unroll
    for (int p = 0; p < 2; ++p) {
        int idx = p * 256 + v;
        int rr = idx >> 5, d = idx & 31;
        int R = r0 + rr, b = R >> 7, t = R & 127;
        se[rr][d] = X[((size_t)b * 129 * 128 + t) * 32 + d];   // X[b,0,t,d]
    }
    __syncthreads();

    float4 bv = make_float4(bias[v], bias[256 + v], bias[512 + v], bias[768 + v]);
    float4 acc[16];
    #pragma unroll
    for (int rr = 0; rr < 16; ++rr) acc[rr] = bv;

    #pragma unroll
    for (int u = 0; u < 32; ++u) {
        float4 w = ek4[u * 256 + v];
        #pragma unroll
        for (int rr = 0; rr < 16; ++rr) {
            float s = se[rr][u];
            acc[rr].x += s * w.x; acc[rr].y += s * w.y;
            acc[rr].z += s * w.z; acc[rr].w += s * w.w;
        }
    }
    #pragma unroll
    for (int rr = 0; rr < 16; ++rr)
        xWp[(size_t)(r0 + rr) * 256 + v] = acc[rr];
}

// ---------------- dec xW GEMM: 32 rows/block, 512 threads ----------------
__global__ __launch_bounds__(512) void xw_gemm_dec(
    const float*  __restrict__ SE,
    const float4* __restrict__ dk4,
    const float*  __restrict__ bias,
    float4* __restrict__ xWp)
{
    const int tid = threadIdx.x;
    const int v = tid & 255;
    const int hh = tid >> 8;               // 0/1
    const int rbase = blockIdx.x * 32;
    __shared__ float se[32][256];

    for (int i = tid; i < 8192; i += 512) {
        int rr = i >> 8, c = i & 255;
        se[rr][c] = SE[(size_t)(rbase + rr) * 256 + c];
    }
    __syncthreads();

    float4 bv = make_float4(bias[v], bias[256 + v], bias[512 + v], bias[768 + v]);
    float4 acc[16];
    #pragma unroll
    for (int rr = 0; rr < 16; ++rr) acc[rr] = bv;

    #pragma unroll 8
    for (int u = 0; u < 256; ++u) {
        float4 w = dk4[u * 256 + v];
        #pragma unroll
        for (int rr = 0; rr < 16; ++rr) {
            float s = se[hh * 16 + rr][u];
            acc[rr].x += s * w.x; acc[rr].y += s * w.y;
            acc[rr].z += s * w.z; acc[rr].w += s * w.w;
        }
    }
    #pragma unroll
    for (int rr = 0; rr < 16; ++rr)
        xWp[(size_t)(rbase + hh * 16 + rr) * 256 + v] = acc[rr];
}

// ---------------- skip-LSTM recurrence: 256 blocks = 4 v-slices x 64 batches ----------------
// bid = slice*64 + b -> all 4 slices of a batch share bid%8 -> same XCD.
// Wave-autonomous staging: each wave's 16-u chunk lies in ONE region; partner-chunk waves
// stage their own rows (self-contained, no barrier to GEMV). 2 barriers/step (around finish).
// sready LDS relay: 3 lanes of wave slice*4+1 poll L2 flags, tag-publish to LDS.
__global__ __launch_bounds__(1024, 4) void rec11(
    const float4*   __restrict__ xW,    // (B*128*256) float4, bias included
    const float4*   __restrict__ rk4,   // (256*256) fp32 gate weights
    const unsigned* __restrict__ kh2,   // (128*256) fp16 skip-weight pairs
    const float*    __restrict__ bias2,
    const float*    __restrict__ s0p,
    float* __restrict__ out,            // (B*128*256)
    float* __restrict__ EX,             // [2][64][4][320] floats
    unsigned* __restrict__ flags,       // [64][4]
    unsigned fbase)
{
    const int b     = blockIdx.x & 63;   // batch
    const int slice = blockIdx.x >> 6;   // v-slice
    const int voff  = slice * 64;
    const int tid   = threadIdx.x;
    const int us    = tid >> 6;          // 0..15 u-chunk (16 u each); uniform per wave
    const int vl    = tid & 63;
    const int v     = voff + vl;
    const int reg   = us >> 2;           // region (slice) this wave's u-chunk belongs to
    const bool own  = (reg == slice);
    const int lane  = vl;

    __shared__ float4 wres[128][64];     // 128 KB: gate rows us*16+0..7
    __shared__ float4 pA[16][64];        // 16 KB
    __shared__ float  pS[16][64];        // 4 KB
    __shared__ float4 h4[256];           // 4 KB
    __shared__ float  pq[4][256];        // 4 KB
    __shared__ unsigned sready[4];

    for (int i = tid; i < 8192; i += 1024) {
        int r = i >> 6, vv = i & 63;
        int cc = r >> 3, j = r & 7;
        wres[r][vv] = rk4[(cc * 16 + j) * 256 + voff + vv];
    }
    float4 wreg[8];
    unsigned kreg[8];
    {
        const float4*   wp = rk4 + (us * 16 + 8) * 256 + v;
        const unsigned* kp = kh2 + (us * 8) * 256 + v;
        #pragma unroll
        for (int j = 0; j < 8; ++j) wreg[j] = wp[j * 256];
        #pragma unroll
        for (int j = 0; j < 8; ++j) kreg[j] = kp[j * 256];
    }
    if (tid < 256) {
        h4[tid] = make_float4(0.f, 0.f, 0.f, 0.f);
        pq[0][tid] = 0.f; pq[1][tid] = 0.f; pq[2][tid] = 0.f; pq[3][tid] = 0.f;
    }
    if (tid < 4) sready[tid] = fbase;
    float cst = 0.f;
    const float s0 = s0p[0];
    const float b2 = bias2[voff + vl];
    unsigned* mflag = flags + b * 4 + slice;
    const bool pollwave = (us == slice * 4 + 1);
    __syncthreads();

    for (int t = 0; t < 128; ++t) {
        const unsigned T = fbase + (unsigned)t;
        // wave0: issue xa load early (used in finish)
        float4 xa = make_float4(0.f, 0.f, 0.f, 0.f);
        if (tid < 64) xa = xW[((size_t)b * 128 + t) * 256 + voff + tid];

        if (t > 0) {
            if (pollwave && lane < 3) {
                // poll the 3 partner flags; relay via LDS tag
                int ps = lane + (lane >= slice ? 1 : 0);
                const unsigned* pf = flags + b * 4 + ps;
                while (__hip_atomic_load(pf, __ATOMIC_RELAXED, __HIP_MEMORY_SCOPE_AGENT) < T) { }
                __hip_atomic_store(&sready[ps], T, __ATOMIC_RELAXED, __HIP_MEMORY_SCOPE_WORKGROUP);
            }
            if (!own) {
                // wait for MY region's partner only (wave-uniform spin on LDS)
                while (__hip_atomic_load(&sready[reg], __ATOMIC_RELAXED, __HIP_MEMORY_SCOPE_WORKGROUP) < T)
                    __builtin_amdgcn_s_sleep(1);
                // self-stage my 16 h4 rows (32 ull, lanes 0-31) + 16 pq entries (lanes 32-47)
                const int sp = (t + 1) & 1;
                const float* srcf = EX + (((size_t)sp * 64 + b) * 4 + reg) * 320;
                if (lane < 32) {
                    // h4 rows us*16..us*16+15 <- EX gates [ (us&3)*16*2 ull .. +32 )
                    const unsigned long long* src = (const unsigned long long*)srcf;
                    int jj = (us & 3) * 32 + lane;
                    unsigned long long d = __hip_atomic_load(src + jj, __ATOMIC_RELAXED, __HIP_MEMORY_SCOPE_AGENT);
                    reinterpret_cast<unsigned long long*>(&h4[reg * 64])[(us & 3) * 32 + lane] = d;
                } else if (lane < 48) {
                    int k = lane - 32;                 // 0..15
                    int uu = (us & 3) * 16 + k;        // row within region
                    unsigned hv = __hip_atomic_load((const unsigned*)(srcf + 256) + uu,
                                                    __ATOMIC_RELAXED, __HIP_MEMORY_SCOPE_AGENT);
                    pq[(t + 3) & 3][reg * 64 + uu] = __uint_as_float(hv);
                }
                asm volatile("s_waitcnt vmcnt(0) lgkmcnt(0)" ::: "memory");
            }
        }

        // GEMV over my 16-u chunk (weights resident; h4/pq rows for my chunk now valid)
        {
            float ai = 0.f, af = 0.f, acg = 0.f, ao = 0.f, as = 0.f;
            const int slot = t & 3;
            #pragma unroll
            for (int j = 0; j < 8; ++j) {
                float4 w = wres[us * 8 + j][vl];
                float4 g = h4[us * 16 + j];
                ai += g.x * w.x; af += g.y * w.y; acg += g.z * w.z; ao += g.w * w.w;
            }
            #pragma unroll
            for (int j = 0; j < 8; ++j) {
                float4 w = wreg[j];
                float4 g = h4[us * 16 + 8 + j];
                ai += g.x * w.x; af += g.y * w.y; acg += g.z * w.z; ao += g.w * w.w;
            }
            #pragma unroll
            for (int j = 0; j < 8; ++j) {
                float2 kk = uph(kreg[j]);
                as += pq[slot][us * 16 + 2 * j] * kk.x + pq[slot][us * 16 + 2 * j + 1] * kk.y;
            }
            pA[us][vl] = make_float4(ai, af, acg, ao);
            pS[us][vl] = as;
        }
        __syncthreads();   // pA/pS complete; also orders prior-step finish writes

        if (tid < 64) {
            float4 A = pA[0][vl];
            float  S = pS[0][vl];
            #pragma unroll
            for (int cc = 1; cc < 16; ++cc) {
                float4 q = pA[cc][vl];
                A.x += q.x; A.y += q.y; A.z += q.z; A.w += q.w;
                S += pS[cc][vl];
            }
            float gi = sigmoidf_(xa.x + A.x);
            float gf = sigmoidf_(xa.y + A.y);
            float cb = tanhf_(xa.z + A.z);
            cst = gf * cst + gi * cb;
            float go = sigmoidf_(xa.w + A.w);
            float hh = go * tanhf_(cst);
            float hs = sigmoidf_(S + b2);
            float hf = s0 * hh + (1.f - s0) * hs;
            h4[voff + vl] = make_float4(gi, gf, cst, go);
            pq[t & 3][voff + vl] = hf;
            out[((size_t)b * 128 + t) * 256 + voff + vl] = hf;
            float* dst = EX + (((size_t)(t & 1) * 64 + b) * 4 + slice) * 320;
            union { float4 f4; unsigned long long u[2]; } gv;
            gv.f4 = make_float4(gi, gf, cst, go);
            __hip_atomic_store((unsigned long long*)dst + 2 * vl,     gv.u[0], __ATOMIC_RELAXED, __HIP_MEMORY_SCOPE_AGENT);
            __hip_atomic_store((unsigned long long*)dst + 2 * vl + 1, gv.u[1], __ATOMIC_RELAXED, __HIP_MEMORY_SCOPE_AGENT);
            __hip_atomic_store((unsigned*)(dst + 256) + vl, __float_as_uint(hf), __ATOMIC_RELAXED, __HIP_MEMORY_SCOPE_AGENT);
            asm volatile("s_waitcnt vmcnt(0)" ::: "memory");
            if (tid == 0)
                __hip_atomic_store(mflag, T + 1u, __ATOMIC_RELAXED, __HIP_MEMORY_SCOPE_AGENT);
        }
        __syncthreads();   // finish writes (h4/pq own region) visible to next step
    }
}

// ---------------- dense split-K, wave-coalesced, spill-free (r12's dense3) ----------------
__global__ __launch_bounds__(512, 4) void dense3(
    const float* __restrict__ SD,    // (64 x 32768)
    const float* __restrict__ dw,    // (32768 x 4096)
    float* __restrict__ P)           // (16 x 64 x 4096)
{
    const int bid = blockIdx.x;
    const int kc = bid >> 5;            // 0..15
    const int bb = (bid >> 3) & 3;      // 0..3
    const int ct = bid & 7;             // 0..7
    const int tid = threadIdx.x;
    const int wv  = tid >> 6;
    const int wvj = wv & 1;
    const int wv2 = wv >> 1;            // 0..3
    const int lane = tid & 63;
    const int j0 = ct * 512 + wvj * 256 + lane * 4;
    const int kbase = kc * 2048;

    __shared__ float sst[16][68];
    __shared__ float red[4][4][520];

    float4 acc[16];
    #pragma unroll
    for (int b = 0; b < 16; ++b) acc[b] = make_float4(0.f, 0.f, 0.f, 0.f);

    for (int k0 = 0; k0 < 2048; k0 += 64) {
        if (tid < 256) {
            int r = tid >> 4, c4 = (tid & 15) * 4;
            float4 s4 = *reinterpret_cast<const float4*>(
                SD + (size_t)(bb * 16 + r) * 32768 + kbase + k0 + c4);
            sst[r][c4] = s4.x; sst[r][c4 + 1] = s4.y; sst[r][c4 + 2] = s4.z; sst[r][c4 + 3] = s4.w;
        }
        __syncthreads();
        #pragma unroll 2
        for (int kk = 0; kk < 16; ++kk) {
            const int krel = kk * 4 + wv2;
            float4 w4 = *reinterpret_cast<const float4*>(
                dw + (size_t)(kbase + k0 + krel) * 4096 + j0);
            #pragma unroll
            for (int b = 0; b < 16; ++b) {
                float s = sst[b][krel];
                acc[b].x += s * w4.x; acc[b].y += s * w4.y;
                acc[b].z += s * w4.z; acc[b].w += s * w4.w;
            }
        }
        __syncthreads();
    }

    for (int bg = 0; bg < 4; ++bg) {
        __syncthreads();
        #pragma unroll
        for (int i = 0; i < 4; ++i) {
            float4 a = acc[bg * 4 + i];
            float* d = &red[wv2][i][wvj * 256 + lane * 4];
            d[0] = a.x; d[1] = a.y; d[2] = a.z; d[3] = a.w;
        }
        __syncthreads();
        {
            int bi = tid >> 7;
            int jj = (tid & 127) * 4;
            float4 s;
            s.x = red[0][bi][jj]     + red[1][bi][jj]     + red[2][bi][jj]     + red[3][bi][jj];
            s.y = red[0][bi][jj + 1] + red[1][bi][jj + 1] + red[2][bi][jj + 1] + red[3][bi][jj + 1];
            s.z = red[0][bi][jj + 2] + red[1][bi][jj + 2] + red[2][bi][jj + 2] + red[3][bi][jj + 2];
            s.w = red[0][bi][jj + 3] + red[1][bi][jj + 3] + red[2][bi][jj + 3] + red[3][bi][jj + 3];
            *reinterpret_cast<float4*>(
                P + ((size_t)(kc * 64 + bb * 16 + bg * 4 + bi) * 4096) + ct * 512 + jj) = s;
        }
    }
}

// ---------------- reduce partials + bias + Z2 ----------------
__global__ __launch_bounds__(256) void reduce_z2(
    const float* __restrict__ P,
    const float* __restrict__ db,
    const float* __restrict__ X,
    const float* __restrict__ fw,
    const float* __restrict__ fbp,
    float* __restrict__ out)
{
    const int o4 = blockIdx.x * 256 + threadIdx.x;   // 0..65535
    const int b  = o4 >> 10;
    const int j4 = o4 & 1023;
    const int j0 = j4 * 4;
    const int i  = j0 >> 5;
    const int m  = j0 & 31;

    float4 acc = *reinterpret_cast<const float4*>(db + j0);
    #pragma unroll
    for (int kc = 0; kc < 16; ++kc) {
        float4 p = *reinterpret_cast<const float4*>(P + (size_t)(kc * 64 + b) * 4096 + j0);
        acc.x += p.x; acc.y += p.y; acc.z += p.z; acc.w += p.w;
    }

    const float* xp = X + ((size_t)(b * 129 + 1 + i) * 128) * 32 + m;
    #pragma unroll 8
    for (int s = 0; s < 128; ++s) {
        float4 xv = *reinterpret_cast<const float4*>(xp + (size_t)s * 32);
        float w = fw[s];
        acc.x += w * xv.x; acc.y += w * xv.y; acc.z += w * xv.z; acc.w += w * xv.w;
    }
    const float fb = fbp[0];
    acc.x += fb; acc.y += fb; acc.z += fb; acc.w += fb;
    *reinterpret_cast<float4*>(out + (size_t)o4 * 4) = acc;
}

extern "C" void kernel_launch(void* const* d_in, const int* in_sizes, int n_in,
                              void* d_out, int out_size, void* d_ws, size_t ws_size,
                              hipStream_t stream) {
    const float* X    = (const float*)d_in[0];
    const float* e_k  = (const float*)d_in[1];
    const float* e_rk = (const float*)d_in[2];
    const float* e_k2 = (const float*)d_in[3];
    const float* e_b  = (const float*)d_in[4];
    const float* e_b2 = (const float*)d_in[5];
    const float* e_s0 = (const float*)d_in[6];
    const float* d_k  = (const float*)d_in[7];
    const float* d_rk = (const float*)d_in[8];
    const float* d_k2 = (const float*)d_in[9];
    const float* d_b  = (const float*)d_in[10];
    const float* d_b2 = (const float*)d_in[11];
    const float* d_s0 = (const float*)d_in[12];
    const float* dw   = (const float*)d_in[13];
    const float* db   = (const float*)d_in[14];
    const float* fw   = (const float*)d_in[15];
    const float* fb   = (const float*)d_in[16];

    float* ws = (float*)d_ws;
    // rk4e 0 | rk4d 262144 | dk4 524288 | ek4 786432 | kh2e 819200 | kh2d 851968
    // EX 884736 | flags 1212416 | xW 1310720 (8M, reused as P) | SE 9699328 | SD 11796480
    float4*   rk4e  = (float4*)(ws);
    float4*   rk4d  = (float4*)(ws + 262144);
    float4*   dk4   = (float4*)(ws + 524288);
    float4*   ek4   = (float4*)(ws + 786432);
    unsigned* kh2e  = (unsigned*)(ws + 819200);
    unsigned* kh2d  = (unsigned*)(ws + 851968);
    float*    EX    = ws + 884736;
    unsigned* flags = (unsigned*)(ws + 1212416);
    float*    xW    = ws + 1310720;
    float*    SE    = ws + 9699328;
    float*    SD    = ws + 11796480;

    float* P = xW;

    hipLaunchKernelGGL(packall, dim3(929), dim3(256), 0, stream,
                       e_rk, d_rk, d_k, e_k, e_k2, d_k2,
                       rk4e, rk4d, dk4, ek4, kh2e, kh2d, flags);
    hipLaunchKernelGGL(xw_gemm_enc, dim3(512), dim3(256), 0, stream,
                       X, ek4, e_b, (float4*)xW);
    hipLaunchKernelGGL(rec11, dim3(256), dim3(1024), 0, stream,
                       (const float4*)xW, rk4e, kh2e, e_b2, e_s0, SE, EX, flags, 0u);
    hipLaunchKernelGGL(xw_gemm_dec, dim3(256), dim3(512), 0, stream,
                       SE, dk4, d_b, (float4*)xW);
    hipLaunchKernelGGL(rec11, dim3(256), dim3(1024), 0, stream,
                       (const float4*)xW, rk4d, kh2d, d_b2, d_s0, SD, EX, flags, 128u);
    hipLaunchKernelGGL(dense3, dim3(512), dim3(512), 0, stream, SD, dw, P);
    hipLaunchKernelGGL(reduce_z2, dim3(256), dim3(256), 0, stream,
                       P, db, X, fw, fb, (float*)d_out);
}

// Round 19
// 1163.019 us; speedup vs baseline: 1.2581x; 1.2581x over previous
//
#include <hip/hip_runtime.h>
#include <hip/hip_fp16.h>

// B=64, T=128, U=256, D_in=32, SKIP=4; dense: (64 x 32768) @ (32768 x 4096)

typedef _Float16 h8 __attribute__((ext_vector_type(8)));
typedef float f4v __attribute__((ext_vector_type(4)));

__device__ __forceinline__ float sigmoidf_(float x) {
    return 1.0f / (1.0f + __expf(-x));
}
__device__ __forceinline__ float tanhf_(float x) {
    float xc = fminf(fmaxf(x, -15.f), 15.f);
    float e = __expf(2.f * xc);
    return (e - 1.f) / (e + 1.f);
}
__device__ __forceinline__ unsigned pkh(float lo, float hi) {
    __half2 h = __halves2half2(__float2half(lo), __float2half(hi));
    return *reinterpret_cast<unsigned*>(&h);
}
__device__ __forceinline__ float2 uph(unsigned u) {
    __half2 h = *reinterpret_cast<__half2*>(&u);
    return __half22float2(h);
}

// ---------------- all weight packing + flag zeroing ----------------
__global__ __launch_bounds__(256) void packall(
    const float* __restrict__ e_rk, const float* __restrict__ d_rk,
    const float* __restrict__ d_k,  const float* __restrict__ e_k,
    const float* __restrict__ e_k2, const float* __restrict__ d_k2,
    float4* __restrict__ rk4e, float4* __restrict__ rk4d,
    float4* __restrict__ dk4,  float4* __restrict__ ek4,
    unsigned* __restrict__ kh2e, unsigned* __restrict__ kh2d,
    unsigned* __restrict__ flags)
{
    const int bx = blockIdx.x, v = threadIdx.x;
    if (bx < 800) {
        const float* src; float4* dst; int row;
        if (bx < 256)      { src = e_rk; dst = rk4e; row = bx; }
        else if (bx < 512) { src = d_rk; dst = rk4d; row = bx - 256; }
        else if (bx < 768) { src = d_k;  dst = dk4;  row = bx - 512; }
        else               { src = e_k;  dst = ek4;  row = bx - 768; }
        const float* s = src + (size_t)row * 1024;
        dst[row * 256 + v] = make_float4(s[v], s[256 + v], s[512 + v], s[768 + v]);
    } else if (bx < 928) {
        const int u2 = bx - 800;   // 0..127
        kh2e[u2 * 256 + v] = pkh(e_k2[(2 * u2) * 256 + v], e_k2[(2 * u2 + 1) * 256 + v]);
        kh2d[u2 * 256 + v] = pkh(d_k2[(2 * u2) * 256 + v], d_k2[(2 * u2 + 1) * 256 + v]);
    } else {
        flags[v] = 0u;             // re-zeroed every launch (graph-safe)
    }
}

// ---------------- enc xW GEMM: K=32 rows gathered from X[:,0] ----------------
__global__ __launch_bounds__(256) void xw_gemm_enc(
    const float*  __restrict__ X,
    const float4* __restrict__ ek4,
    const float*  __restrict__ bias,
    float4* __restrict__ xWp)
{
    const int v = threadIdx.x;
    const int r0 = blockIdx.x * 16;
    __shared__ float se[16][32];

    #pragma unroll
    for (int p = 0; p < 2; ++p) {
        int idx = p * 256 + v;
        int rr = idx >> 5, d = idx & 31;
        int R = r0 + rr, b = R >> 7, t = R & 127;
        se[rr][d] = X[((size_t)b * 129 * 128 + t) * 32 + d];   // X[b,0,t,d]
    }
    __syncthreads();

    float4 bv = make_float4(bias[v], bias[256 + v], bias[512 + v], bias[768 + v]);
    float4 acc[16];
    #pragma unroll
    for (int rr = 0; rr < 16; ++rr) acc[rr] = bv;

    #pragma unroll
    for (int u = 0; u < 32; ++u) {
        float4 w = ek4[u * 256 + v];
        #pragma unroll
        for (int rr = 0; rr < 16; ++rr) {
            float s = se[rr][u];
            acc[rr].x += s * w.x; acc[rr].y += s * w.y;
            acc[rr].z += s * w.z; acc[rr].w += s * w.w;
        }
    }
    #pragma unroll
    for (int rr = 0; rr < 16; ++rr)
        xWp[(size_t)(r0 + rr) * 256 + v] = acc[rr];
}

// ---------------- dec xW GEMM: 32 rows/block, 512 threads ----------------
__global__ __launch_bounds__(512) void xw_gemm_dec(
    const float*  __restrict__ SE,
    const float4* __restrict__ dk4,
    const float*  __restrict__ bias,
    float4* __restrict__ xWp)
{
    const int tid = threadIdx.x;
    const int v = tid & 255;
    const int hh = tid >> 8;               // 0/1
    const int rbase = blockIdx.x * 32;
    __shared__ float se[32][256];

    for (int i = tid; i < 8192; i += 512) {
        int rr = i >> 8, c = i & 255;
        se[rr][c] = SE[(size_t)(rbase + rr) * 256 + c];
    }
    __syncthreads();

    float4 bv = make_float4(bias[v], bias[256 + v], bias[512 + v], bias[768 + v]);
    float4 acc[16];
    #pragma unroll
    for (int rr = 0; rr < 16; ++rr) acc[rr] = bv;

    #pragma unroll 8
    for (int u = 0; u < 256; ++u) {
        float4 w = dk4[u * 256 + v];
        #pragma unroll
        for (int rr = 0; rr < 16; ++rr) {
            float s = se[hh * 16 + rr][u];
            acc[rr].x += s * w.x; acc[rr].y += s * w.y;
            acc[rr].z += s * w.z; acc[rr].w += s * w.w;
        }
    }
    #pragma unroll
    for (int rr = 0; rr < 16; ++rr)
        xWp[(size_t)(rbase + hh * 16 + rr) * 256 + v] = acc[rr];
}

// ---------------- skip-LSTM recurrence (rec9, round-15 proven) ----------------
__global__ __launch_bounds__(1024, 4) void rec9(
    const float4*   __restrict__ xW,
    const float4*   __restrict__ rk4,
    const unsigned* __restrict__ kh2,
    const float*    __restrict__ bias2,
    const float*    __restrict__ s0p,
    float* __restrict__ out,
    float* __restrict__ EX,             // [2][64][4][320] floats
    unsigned* __restrict__ flags,       // [64][4]
    unsigned fbase)
{
    const int b     = blockIdx.x & 63;
    const int slice = blockIdx.x >> 6;
    const int voff  = slice * 64;
    const int tid   = threadIdx.x;
    const int us    = tid >> 6;
    const int vl    = tid & 63;
    const int v     = voff + vl;

    __shared__ float4 wres[128][64];
    __shared__ float4 pA[16][64];
    __shared__ float  pS[16][64];
    __shared__ float4 h4[256];
    __shared__ float  pq[4][256];

    for (int i = tid; i < 8192; i += 1024) {
        int r = i >> 6, vv = i & 63;
        int cc = r >> 3, j = r & 7;
        wres[r][vv] = rk4[(cc * 16 + j) * 256 + voff + vv];
    }
    float4 wreg[8];
    unsigned kreg[8];
    {
        const float4*   wp = rk4 + (us * 16 + 8) * 256 + v;
        const unsigned* kp = kh2 + (us * 8) * 256 + v;
        #pragma unroll
        for (int j = 0; j < 8; ++j) wreg[j] = wp[j * 256];
        #pragma unroll
        for (int j = 0; j < 8; ++j) kreg[j] = kp[j * 256];
    }
    if (tid < 256) {
        h4[tid] = make_float4(0.f, 0.f, 0.f, 0.f);
        pq[0][tid] = 0.f; pq[1][tid] = 0.f; pq[2][tid] = 0.f; pq[3][tid] = 0.f;
    }
    float cst = 0.f;
    const float s0 = s0p[0];
    const float b2 = bias2[voff + vl];
    unsigned* mflag = flags + b * 4 + slice;
    __syncthreads();

    for (int t = 0; t < 128; ++t) {
        float4 xa = make_float4(0.f, 0.f, 0.f, 0.f);
        if (tid < 64) xa = xW[((size_t)b * 128 + t) * 256 + voff + tid];
        if (t > 0 && tid < 3) {
            int ps = tid + (tid >= slice ? 1 : 0);
            const unsigned* pf = flags + b * 4 + ps;
            while (__hip_atomic_load(pf, __ATOMIC_RELAXED, __HIP_MEMORY_SCOPE_AGENT) < fbase + (unsigned)t)
                __builtin_amdgcn_s_sleep(2);
        }
        __syncthreads();
        if (t > 0) {
            const int sp = (t + 1) & 1;
            if (tid < 480) {
                int pi = tid / 160;
                int j  = tid - pi * 160;
                int ps = pi + (pi >= slice ? 1 : 0);
                const unsigned long long* src = (const unsigned long long*)
                    (EX + (((size_t)sp * 64 + b) * 4 + ps) * 320);
                unsigned long long d = __hip_atomic_load(src + j, __ATOMIC_RELAXED, __HIP_MEMORY_SCOPE_AGENT);
                if (j < 128) {
                    reinterpret_cast<unsigned long long*>(&h4[ps * 64])[j] = d;
                } else {
                    int k = j - 128;
                    union { unsigned long long u; float f[2]; } cv; cv.u = d;
                    pq[(t + 3) & 3][ps * 64 + 2 * k]     = cv.f[0];
                    pq[(t + 3) & 3][ps * 64 + 2 * k + 1] = cv.f[1];
                }
            }
        }
        __syncthreads();

        float ai = 0.f, af = 0.f, acg = 0.f, ao = 0.f, as = 0.f;
        const int slot = t & 3;
        #pragma unroll
        for (int j = 0; j < 8; ++j) {
            float4 w = wres[us * 8 + j][vl];
            float4 g = h4[us * 16 + j];
            ai += g.x * w.x; af += g.y * w.y; acg += g.z * w.z; ao += g.w * w.w;
        }
        #pragma unroll
        for (int j = 0; j < 8; ++j) {
            float4 w = wreg[j];
            float4 g = h4[us * 16 + 8 + j];
            ai += g.x * w.x; af += g.y * w.y; acg += g.z * w.z; ao += g.w * w.w;
        }
        #pragma unroll
        for (int j = 0; j < 8; ++j) {
            float2 kk = uph(kreg[j]);
            as += pq[slot][us * 16 + 2 * j] * kk.x + pq[slot][us * 16 + 2 * j + 1] * kk.y;
        }
        pA[us][vl] = make_float4(ai, af, acg, ao);
        pS[us][vl] = as;
        __syncthreads();

        if (tid < 64) {
            float4 A = pA[0][vl];
            float  S = pS[0][vl];
            #pragma unroll
            for (int cc = 1; cc < 16; ++cc) {
                float4 q = pA[cc][vl];
                A.x += q.x; A.y += q.y; A.z += q.z; A.w += q.w;
                S += pS[cc][vl];
            }
            float gi = sigmoidf_(xa.x + A.x);
            float gf = sigmoidf_(xa.y + A.y);
            float cb = tanhf_(xa.z + A.z);
            cst = gf * cst + gi * cb;
            float go = sigmoidf_(xa.w + A.w);
            float hh = go * tanhf_(cst);
            float hs = sigmoidf_(S + b2);
            float hf = s0 * hh + (1.f - s0) * hs;
            h4[voff + vl] = make_float4(gi, gf, cst, go);
            pq[slot][voff + vl] = hf;
            out[((size_t)b * 128 + t) * 256 + voff + vl] = hf;
            float* dst = EX + (((size_t)(t & 1) * 64 + b) * 4 + slice) * 320;
            union { float4 f4; unsigned long long u[2]; } gv;
            gv.f4 = make_float4(gi, gf, cst, go);
            __hip_atomic_store((unsigned long long*)dst + 2 * vl,     gv.u[0], __ATOMIC_RELAXED, __HIP_MEMORY_SCOPE_AGENT);
            __hip_atomic_store((unsigned long long*)dst + 2 * vl + 1, gv.u[1], __ATOMIC_RELAXED, __HIP_MEMORY_SCOPE_AGENT);
            __hip_atomic_store(dst + 256 + vl, hf, __ATOMIC_RELAXED, __HIP_MEMORY_SCOPE_AGENT);
        }
        __syncthreads();
        if (tid == 0)
            __hip_atomic_store(mflag, fbase + (unsigned)(t + 1), __ATOMIC_RELAXED, __HIP_MEMORY_SCOPE_AGENT);
    }
}

// ---------------- SD fp32 -> fp16 ----------------
__global__ __launch_bounds__(256) void cvt_sd(const float* __restrict__ SD, _Float16* __restrict__ SDh)
{
    const int i = (blockIdx.x * 256 + threadIdx.x) * 8;
    float4 a = *reinterpret_cast<const float4*>(SD + i);
    float4 b = *reinterpret_cast<const float4*>(SD + i + 4);
    h8 h;
    h[0] = (_Float16)a.x; h[1] = (_Float16)a.y; h[2] = (_Float16)a.z; h[3] = (_Float16)a.w;
    h[4] = (_Float16)b.x; h[5] = (_Float16)b.y; h[6] = (_Float16)b.z; h[7] = (_Float16)b.w;
    *reinterpret_cast<h8*>(SDh + i) = h;
}

// ---------------- dense via MFMA fp16, in-kernel B conversion ----------------
// grid 256: kc = bid>>6 (split-K 4), nb = bid&63 (64-col tiles). Block 256 thr = 4 waves.
// Wave w owns n-strip 16w; per K-panel (64 rows) stage dw -> fp16 transposed LDS tile,
// then 2 x (4 A-frag loads from SDh + 1 B-frag LDS read + 4 MFMA 16x16x32).
__global__ __launch_bounds__(256, 4) void mfma_dense(
    const _Float16* __restrict__ SDh,   // (64 x 32768)
    const float*    __restrict__ dw,    // (32768 x 4096)
    float* __restrict__ P)              // (4 x 64 x 4096)
{
    const int nb  = blockIdx.x & 63;
    const int kc  = blockIdx.x >> 6;    // 0..3
    const int n0  = nb * 64;
    const int tid = threadIdx.x;
    const int w   = tid >> 6;           // wave 0..3
    const int l   = tid & 63;
    const int ar  = l & 15;
    const int ko8 = (l >> 4) * 8;       // k-offset (halfs) within a 32-k window

    __shared__ unsigned Bt[64][36];     // [n][k2] half2-packed; row 36 dwords = 72 halfs (64+pad)

    f4v acc[4] = {{0.f,0.f,0.f,0.f},{0.f,0.f,0.f,0.f},{0.f,0.f,0.f,0.f},{0.f,0.f,0.f,0.f}};

    for (int kk = 0; kk < 128; ++kk) {
        const int kg = kc * 8192 + kk * 64;
        // stage: wave w packs k-pairs k2 = 8w..8w+7 for its 64 n-lanes
        #pragma unroll
        for (int i = 0; i < 8; ++i) {
            int k2 = w * 8 + i;
            float lo = dw[(size_t)(kg + 2 * k2)     * 4096 + n0 + l];
            float hi = dw[(size_t)(kg + 2 * k2 + 1) * 4096 + n0 + l];
            Bt[l][k2] = pkh(lo, hi);
        }
        __syncthreads();
        #pragma unroll
        for (int hs = 0; hs < 2; ++hs) {
            const int kw = kg + hs * 32;
            h8 bf = *reinterpret_cast<const h8*>(
                      reinterpret_cast<const _Float16*>(&Bt[16 * w + ar][0]) + hs * 32 + ko8);
            #pragma unroll
            for (int mt = 0; mt < 4; ++mt) {
                h8 af = *reinterpret_cast<const h8*>(
                          SDh + (size_t)(mt * 16 + ar) * 32768 + kw + ko8);
                acc[mt] = __builtin_amdgcn_mfma_f32_16x16x32_f16(af, bf, acc[mt], 0, 0, 0);
            }
        }
        __syncthreads();
    }
    #pragma unroll
    for (int mt = 0; mt < 4; ++mt) {
        #pragma unroll
        for (int r = 0; r < 4; ++r) {
            P[(size_t)(kc * 64 + mt * 16 + (l >> 4) * 4 + r) * 4096 + n0 + 16 * w + ar] = acc[mt][r];
        }
    }
}

// ---------------- reduce partials + bias + Z2 ----------------
__global__ __launch_bounds__(256) void reduce_z2(
    const float* __restrict__ P,
    const float* __restrict__ db,
    const float* __restrict__ X,
    const float* __restrict__ fw,
    const float* __restrict__ fbp,
    float* __restrict__ out)
{
    const int o4 = blockIdx.x * 256 + threadIdx.x;   // 0..65535
    const int b  = o4 >> 10;
    const int j4 = o4 & 1023;
    const int j0 = j4 * 4;
    const int i  = j0 >> 5;
    const int m  = j0 & 31;

    float4 acc = *reinterpret_cast<const float4*>(db + j0);
    #pragma unroll
    for (int kc = 0; kc < 4; ++kc) {
        float4 p = *reinterpret_cast<const float4*>(P + (size_t)(kc * 64 + b) * 4096 + j0);
        acc.x += p.x; acc.y += p.y; acc.z += p.z; acc.w += p.w;
    }

    const float* xp = X + ((size_t)(b * 129 + 1 + i) * 128) * 32 + m;
    #pragma unroll 8
    for (int s = 0; s < 128; ++s) {
        float4 xv = *reinterpret_cast<const float4*>(xp + (size_t)s * 32);
        float w = fw[s];
        acc.x += w * xv.x; acc.y += w * xv.y; acc.z += w * xv.z; acc.w += w * xv.w;
    }
    const float fb = fbp[0];
    acc.x += fb; acc.y += fb; acc.z += fb; acc.w += fb;
    *reinterpret_cast<float4*>(out + (size_t)o4 * 4) = acc;
}

extern "C" void kernel_launch(void* const* d_in, const int* in_sizes, int n_in,
                              void* d_out, int out_size, void* d_ws, size_t ws_size,
                              hipStream_t stream) {
    const float* X    = (const float*)d_in[0];
    const float* e_k  = (const float*)d_in[1];
    const float* e_rk = (const float*)d_in[2];
    const float* e_k2 = (const float*)d_in[3];
    const float* e_b  = (const float*)d_in[4];
    const float* e_b2 = (const float*)d_in[5];
    const float* e_s0 = (const float*)d_in[6];
    const float* d_k  = (const float*)d_in[7];
    const float* d_rk = (const float*)d_in[8];
    const float* d_k2 = (const float*)d_in[9];
    const float* d_b  = (const float*)d_in[10];
    const float* d_b2 = (const float*)d_in[11];
    const float* d_s0 = (const float*)d_in[12];
    const float* dw   = (const float*)d_in[13];
    const float* db   = (const float*)d_in[14];
    const float* fw   = (const float*)d_in[15];
    const float* fb   = (const float*)d_in[16];

    float* ws = (float*)d_ws;
    // rk4e 0 | rk4d 262144 | dk4 524288 | ek4 786432 | kh2e 819200 | kh2d 851968
    // EX 884736 (+327680) | flags 1212416 | xW 1310720 (8M; reused: P 4M @1310720,
    // SDh 1M-floats @5505024) | SE 9699328 (2M) | SD 11796480 (2M)
    float4*   rk4e  = (float4*)(ws);
    float4*   rk4d  = (float4*)(ws + 262144);
    float4*   dk4   = (float4*)(ws + 524288);
    float4*   ek4   = (float4*)(ws + 786432);
    unsigned* kh2e  = (unsigned*)(ws + 819200);
    unsigned* kh2d  = (unsigned*)(ws + 851968);
    float*    EX    = ws + 884736;
    unsigned* flags = (unsigned*)(ws + 1212416);
    float*    xW    = ws + 1310720;
    float*    SE    = ws + 9699328;
    float*    SD    = ws + 11796480;

    float*     P   = xW;                          // 4*64*4096 = 1M... (4 MB) fits
    _Float16*  SDh = (_Float16*)(ws + 5505024);   // 2M halfs = 1M floats

    hipLaunchKernelGGL(packall, dim3(929), dim3(256), 0, stream,
                       e_rk, d_rk, d_k, e_k, e_k2, d_k2,
                       rk4e, rk4d, dk4, ek4, kh2e, kh2d, flags);
    hipLaunchKernelGGL(xw_gemm_enc, dim3(512), dim3(256), 0, stream,
                       X, ek4, e_b, (float4*)xW);
    hipLaunchKernelGGL(rec9, dim3(256), dim3(1024), 0, stream,
                       (const float4*)xW, rk4e, kh2e, e_b2, e_s0, SE, EX, flags, 0u);
    hipLaunchKernelGGL(xw_gemm_dec, dim3(256), dim3(512), 0, stream,
                       SE, dk4, d_b, (float4*)xW);
    hipLaunchKernelGGL(rec9, dim3(256), dim3(1024), 0, stream,
                       (const float4*)xW, rk4d, kh2d, d_b2, d_s0, SD, EX, flags, 128u);
    hipLaunchKernelGGL(cvt_sd, dim3(1024), dim3(256), 0, stream, SD, SDh);
    hipLaunchKernelGGL(mfma_dense, dim3(256), dim3(256), 0, stream, SDh, dw, P);
    hipLaunchKernelGGL(reduce_z2, dim3(256), dim3(256), 0, stream,
                       P, db, X, fw, fb, (float*)d_out);
}